// Round 4
// baseline (134.789 us; speedup 1.0000x reference)
//
#include <hip/hip_runtime.h>
#include <stdint.h>

// DepthAwareConv2d: out = conv2d(x * depth, weight, pad=1) + bias
// (depth is channel-independent, so the depth-modulated im2col GEMM factors
//  into a plain 3x3 conv of xd = x*depth).
//
// R10 = R9 + occupancy fix. R9 post-mortem: bank conflicts 2.36M -> 0 with no
// time change -> latency-bound, not LDS-bound. Occupancy was 2 waves/SIMD
// (acc[4][8] = 128 AGPR + 128 VGPR = 256 unified regs) and 2 blocks/CU.
//  conv: block tile 128o x 2rows x 64px (grid 1024), wave tile 64o x 1row x
//        64px -> acc[4][4] = 64 AGPR, ~145 total regs -> 3 waves/SIMD
//        (launch_bounds(256,3)); LDS strip 4rows x 66px x 32ch = 16,896 B,
//        dbuf 33,792 B -> 3 blocks/CU co-resident with independent barrier
//        phases. Staging: 1 chunk/thread/row, rows spread over taps 0..3
//        (tails tap 4) -> stage done 4+ taps before the phase barrier.
//        Keeps: R9 bank swizzle (pre-swizzled source + XOR read), T-contig
//        wt2 frag stream, a-frag ping-pong, setprio around MFMA cluster.
//  prep: unchanged R6 structure + R8 T-contiguous weight relayout.

#define C_IN 128
#define O_OUT 256
#define HW 128
#define NB 4
#define PADW 130

#define XD_ELEMS ((size_t)NB * PADW * PADW * C_IN)
#define XD_BYTES (XD_ELEMS * 2)          // 17,305,600 B
#define WT_ELEMS ((size_t)O_OUT * C_IN * 9)
#define WT_BYTES (WT_ELEMS * 2)          // 589,824 B

typedef __attribute__((ext_vector_type(8))) short short8;  // 8 bf16 (4 VGPRs)
typedef __attribute__((ext_vector_type(4))) float f32x4;
typedef __attribute__((ext_vector_type(2))) float f32x2;
typedef __attribute__((ext_vector_type(4))) unsigned uint4v;

__device__ __forceinline__ unsigned f2bf_bits(float f) {
  unsigned u = __builtin_bit_cast(unsigned, f);
  return (u + 0x7fffu + ((u >> 16) & 1u)) >> 16;   // RNE, inputs finite
}

__device__ __forceinline__ void async_load16(const void* g, void* l) {
  __builtin_amdgcn_global_load_lds(
      (__attribute__((address_space(1))) void*)g,
      (__attribute__((address_space(3))) void*)l, 16, 0, 0);
}

// ---- prep (single dispatch): xd rows + halo + weight frag-relayout ---------
// Blocks 0..511   : one (n,y) row. Coalesced float2 reads of x, scale by
//                   depth, c-major LDS transpose, coalesced NHWC writes.
// Blocks 512..515 : zero halo rows 0 and 129 of image n.
// Blocks 516..579 : wt2 in MFMA-A-fragment order, contiguous per (s,T):
//   gid = o0*147456 + s*4096 + T*512 + lane*8 + j   (shorts)
//   o = o0*128 + T*16 + (lane&15)
//   cc = s/9; tap = s%9; c = cc*32 + (lane>>4)*8 + j
__global__ __launch_bounds__(256) void prep_all(const float* __restrict__ x,
                                                const float* __restrict__ depth,
                                                const float* __restrict__ w,
                                                short* __restrict__ xd,
                                                short* __restrict__ wt2) {
  const int R = blockIdx.x;
  const int tid = threadIdx.x;

  if (R >= NB * HW + NB) {                  // ---- weight blocks
    int gid = (R - (NB * HW + NB)) * 4608 + tid;   // 64 * 4608 = 294912
#pragma unroll
    for (int i = 0; i < 18; ++i, gid += 256) {
      const int j = gid & 7;
      const int lane = (gid >> 3) & 63;
      const int T = (gid >> 9) & 7;        // frag row-block 0..7 (o = T*16+ln)
      const int g2 = gid >> 12;
      const int s = g2 % 36;               // K-slot in conv order: cc*9 + tap
      const int o0 = g2 / 36;
      const int ln = lane & 15, q = lane >> 4;
      const int o = (o0 << 7) + (T << 4) + ln;
      const int cc = s / 9;
      const int tap = s % 9;
      const int c = (cc << 5) + (q << 3) + j;
      wt2[gid] = (short)f2bf_bits(w[((size_t)o * C_IN + c) * 9 + tap]);
    }
    return;
  }

  if (R >= NB * HW) {                       // ---- halo-row zero blocks
    const int n = R - NB * HW;
    uint4v* base0 = (uint4v*)(xd + (size_t)n * PADW * PADW * C_IN);
    uint4v* base1 = (uint4v*)(xd + ((size_t)n * PADW + (PADW - 1)) * PADW * C_IN);
    const uint4v z = {0u, 0u, 0u, 0u};
    const int per_row = PADW * C_IN * 2 / 16;   // 2080 uint4 per padded row
    for (int i = tid; i < per_row; i += 256) {
      base0[i] = z;
      base1[i] = z;
    }
    return;
  }

  // ---- row-transform blocks (R6 version)
  __shared__ short s[C_IN * PADW];   // c-major: s[c*130 + px]

  const int n = R >> 7, y = R & 127;
  const int lane = tid & 63;
  const int wave = tid >> 6;

  // zero the two edge pixels of this padded row (x=0 and x=129)
  {
    unsigned* row = (unsigned*)(xd + ((size_t)(n * PADW + y + 1) * PADW) * C_IN);
    if (tid < 64) row[tid] = 0u;                              // pixel 0
    else if (tid < 128) row[(size_t)(PADW - 1) * 64 + (tid - 64)] = 0u;  // pixel 129
  }

  // phase 1: read x (float2, coalesced), scale, dword-write to LDS (c-major)
  const f32x2 d2 = *(const f32x2*)(depth + ((size_t)n * HW + y) * HW + 2 * lane);
  const float* xrow = x + (((size_t)n * C_IN) * HW + y) * HW + 2 * lane;
  unsigned* s32 = (unsigned*)s;
#pragma unroll 8
  for (int ci = 0; ci < 32; ++ci) {
    const int c = ci * 4 + wave;
    const f32x2 v = *(const f32x2*)(xrow + (size_t)c * HW * HW);
    s32[c * 65 + lane] = f2bf_bits(v.x * d2.x) | (f2bf_bits(v.y * d2.y) << 16);
  }
  __syncthreads();

  // phase 2: coalesced NHWC write (pixels 1..128 of the padded row)
  const unsigned short* s16 = (const unsigned short*)s;
  unsigned* orow = (unsigned*)(xd + ((size_t)(n * PADW + y + 1) * PADW + 1) * C_IN);
#pragma unroll 8
  for (int i = 0; i < 32; ++i) {
    const int flat = tid + i * 256;      // 0..8191 dwords
    const int px = flat >> 6, cp = flat & 63;
    const unsigned lo = s16[(2 * cp) * PADW + px];
    const unsigned hi = s16[(2 * cp + 1) * PADW + px];
    orow[flat] = lo | (hi << 16);
  }
}

// ---- main MFMA implicit-GEMM conv ------------------------------------------
// Block: 256 threads (4 waves: wm = o-half, wn = row), tile 128o x 2row x 64px.
// Wave tile 64o x 1row x 64px: acc[4][4]. K = 1152 as (cc 0..3) x (tap 0..8).
// LDS strip per phase: 4 padded rows x 66 px x 32 ch (16,896 B), double-
// buffered. Staging: thread tid owns chunk k=tid of each row (px=tid>>2,
// chq pre-swizzled); rows of phase cc+1 issued at taps 0..3, px64/65 tails
// (8 lanes x 4 rows) at tap 4 -> stage completes ~4 taps before the barrier.
// B-read swizzle: chq' = q ^ ((px_local>>1)&3), u-invariant (u*16 px step).
__global__ __launch_bounds__(256, 3) void conv_mfma(
    const short* __restrict__ xd, const short* __restrict__ wt2,
    const float* __restrict__ bias, float* __restrict__ out) {
  __shared__ __align__(16) short xbuf[2][8448];   // [4 rows][66 px][4 chq][8 ch]

  const int tid = threadIdx.x;
  const int bx = blockIdx.x;            // n*128 + ypair*2 + xh
  const int n = bx >> 7;
  const int yp = (bx >> 1) & 63;
  const int xh = bx & 1;
  const int y = yp << 1;                // first of two output rows
  const int x0 = xh << 6;               // first output col (and strip col base)
  const int o0b = blockIdx.y;           // o tile (x128)
  const int lane = tid & 63;
  const int wave = tid >> 6;
  const int wm = wave & 1, wn = wave >> 1;
  const int ln = lane & 15, q = lane >> 4;

  // W fragment stream base (shorts): frag (s,T) contiguous 1KB, T = wm*4+t
  const short* wbase = wt2 + (size_t)o0b * 147456 + (wm << 11) + (lane << 3);

  // staging: main chunk k=tid of each row; px = tid>>2, chq source
  // pre-swizzled q_src = (tid&3)^((tid>>3)&3). Row r adds 130*128 shorts.
  const short* xsrc0 = xd + ((size_t)(n * PADW + y) * PADW + x0 + (tid >> 2)) * C_IN +
                       ((tid & 3) ^ ((tid >> 3) & 3)) * 8;
  // tail (tid<8): px = 64+(tid>>2), chq = tid&3 ((k>>3)&3 == 0 for k=256..263)
  const short* xsrcT = xd + ((size_t)(n * PADW + y) * PADW + x0 + 64 + (tid >> 2)) * C_IN +
                       (tid & 3) * 8;

  f32x4 acc[4][4] = {};
  short8 areg[2][4];

  auto loadA = [&](int s, int p) {
#pragma unroll
    for (int t = 0; t < 4; ++t)
      areg[p][t] = *(const short8*)(wbase + (size_t)s * 4096 + t * 512);
  };
  // stage row r of phase cc into buffer b (one chunk per thread)
  auto stageRow = [&](int cc, int b, int r) {
    async_load16(xsrc0 + (cc << 5) + r * (PADW * C_IN),
                 &xbuf[b][0] + tid * 8 + r * 2112);
  };
  auto stageTail = [&](int cc, int b) {
    if (tid < 8) {
#pragma unroll
      for (int r = 0; r < 4; ++r)
        async_load16(xsrcT + (cc << 5) + r * (PADW * C_IN),
                     &xbuf[b][0] + r * 2112 + 2048 + tid * 8);
    }
  };

  {  // prologue: stage strip cc=0 into buf0
#pragma unroll
    for (int r = 0; r < 4; ++r) stageRow(0, 0, r);
    stageTail(0, 0);
  }
  loadA(0, 0);
  __syncthreads();   // buf0 ready

#pragma unroll
  for (int cc = 0; cc < 4; ++cc) {
#pragma unroll
    for (int tap = 0; tap < 9; ++tap) {
      const int s = cc * 9 + tap;
      if (s + 1 < 36) loadA(s + 1, (s + 1) & 1);   // prefetch next a-frags

      if (cc + 1 < 4) {   // spread next-strip staging across taps (after loadA!)
        if (tap < 4) stageRow(cc + 1, (cc + 1) & 1, tap);
        else if (tap == 4) stageTail(cc + 1, (cc + 1) & 1);
      }

      const int ti = tap / 3, tj = tap % 3;        // static under unroll
      const int row_s = wn + ti;                   // strip row 0..3
      const int pl0 = tj + ln;                     // px_local for u=0
      const int kq = (q ^ ((pl0 >> 1) & 3)) << 3;  // bank swizzle (u-invariant)
      const short* bb = &xbuf[cc & 1][0] + row_s * 2112 + pl0 * 32 + kq;

      short8 b[4];
#pragma unroll
      for (int u = 0; u < 4; ++u)
        b[u] = *(const short8*)(bb + (u << 9));
      __builtin_amdgcn_s_setprio(1);
#pragma unroll
      for (int t = 0; t < 4; ++t)
#pragma unroll
        for (int u = 0; u < 4; ++u)
          acc[t][u] = __builtin_amdgcn_mfma_f32_16x16x32_bf16(
              areg[s & 1][t], b[u], acc[t][u], 0, 0, 0);
      __builtin_amdgcn_s_setprio(0);
    }
    if (cc + 1 < 4) __syncthreads();   // buf(cc+1) staged+drained; buf(cc) free
  }

  // epilogue: D layout col=lane&15 (pixel), row=q*4+r (o)
  const int yrow = y + wn;
#pragma unroll
  for (int t = 0; t < 4; ++t) {
    const int ob = (o0b << 7) + (wm << 6) + (t << 4) + (q << 2);
#pragma unroll
    for (int u = 0; u < 4; ++u) {
      const int xcol = x0 + (u << 4) + ln;        // output col
#pragma unroll
      for (int r = 0; r < 4; ++r) {
        const int o = ob + r;
        out[(((size_t)n * O_OUT + o) * HW + yrow) * HW + xcol] =
            acc[t][u][r] + bias[o];
      }
    }
  }
}

// ---- fallback (only if ws_size is too small): naive direct conv ------------
__global__ void conv_naive(const float* __restrict__ x,
                           const float* __restrict__ depth,
                           const float* __restrict__ w,
                           const float* __restrict__ bias,
                           float* __restrict__ out) {
  const int gid = blockIdx.x * 256 + threadIdx.x;
  if (gid >= NB * O_OUT * HW * HW) return;
  const int xc = gid & 127;
  const int y = (gid >> 7) & 127;
  const int o = (gid >> 14) & 255;
  const int n = gid >> 22;
  float s = bias[o];
  for (int c = 0; c < C_IN; ++c)
    for (int i = 0; i < 3; ++i) {
      const int yy = y + i - 1;
      if (yy < 0 || yy >= HW) continue;
      for (int j = 0; j < 3; ++j) {
        const int xx = xc + j - 1;
        if (xx < 0 || xx >= HW) continue;
        s += w[((o * C_IN + c) * 3 + i) * 3 + j] *
             x[(((size_t)n * C_IN + c) * HW + yy) * HW + xx] *
             depth[((size_t)n * HW + yy) * HW + xx];
      }
    }
  out[gid] = s;
}

extern "C" void kernel_launch(void* const* d_in, const int* in_sizes, int n_in,
                              void* d_out, int out_size, void* d_ws, size_t ws_size,
                              hipStream_t stream) {
  const float* x = (const float*)d_in[0];
  const float* depth = (const float*)d_in[1];
  // d_in[2] = camera_params (unused by reference)
  const float* weight = (const float*)d_in[3];
  const float* bias = (const float*)d_in[4];
  float* out = (float*)d_out;

  const size_t need = XD_BYTES + WT_BYTES;
  if (ws_size < need) {
    conv_naive<<<(NB * O_OUT * HW * HW + 255) / 256, 256, 0, stream>>>(
        x, depth, weight, bias, out);
    return;
  }

  short* xd = (short*)d_ws;
  short* wt2 = (short*)((char*)d_ws + XD_BYTES);

  prep_all<<<NB * HW + NB + 64, 256, 0, stream>>>(x, depth, weight, xd, wt2);
  conv_mfma<<<dim3(NB * HW, 2), 256, 0, stream>>>(xd, wt2, bias, out);
}

// Round 6
// 132.157 us; speedup vs baseline: 1.0199x; 1.0199x over previous
//
#include <hip/hip_runtime.h>
#include <stdint.h>

// DepthAwareConv2d: out = conv2d(x * depth, weight, pad=1) + bias
// (depth is channel-independent, so the depth-modulated im2col GEMM factors
//  into a plain 3x3 conv of xd = x*depth).
//
// R12 = R11 with the grid-size bug fixed (R11 launched 1024 blocks for a
// 512-block decomposition -> n up to 7 -> OOB -> core dump).
// Conv is R9 (best: 42.6us) + XCD-aware swizzle over a FLAT 512 grid:
//   swz = (bid&7)*64 + (bid>>3)   (bijective: 512 % 8 == 0)
// Each XCD owns 64 consecutive swz = 32 consecutive bx (~2.1MB xd slice,
// fits per-XCD 4MB L2); both o0b tiles of a bx are time-adjacent. Theory:
// vmcnt retires in order, so each tap's areg wait also waits on the previous
// tap's global_load_lds stage chunk; making stage chunks L2 hits (~200cy vs
// ~900cy HBM) takes them off the A-frag critical path.
//  conv: R9 structure: 4 waves (wm x wn), tile 128o x 2rows x 128px,
//        acc[4][8]; dbuf strips, staging spread over taps after loadA;
//        bank swizzle (pre-swizzled source + XOR read, conflicts == 0).
//  prep: unchanged R6 structure + T-contiguous weight relayout.

#define C_IN 128
#define O_OUT 256
#define HW 128
#define NB 4
#define PADW 130

#define XD_ELEMS ((size_t)NB * PADW * PADW * C_IN)
#define XD_BYTES (XD_ELEMS * 2)          // 17,305,600 B
#define WT_ELEMS ((size_t)O_OUT * C_IN * 9)
#define WT_BYTES (WT_ELEMS * 2)          // 589,824 B

typedef __attribute__((ext_vector_type(8))) short short8;  // 8 bf16 (4 VGPRs)
typedef __attribute__((ext_vector_type(4))) float f32x4;
typedef __attribute__((ext_vector_type(2))) float f32x2;
typedef __attribute__((ext_vector_type(4))) unsigned uint4v;

__device__ __forceinline__ unsigned f2bf_bits(float f) {
  unsigned u = __builtin_bit_cast(unsigned, f);
  return (u + 0x7fffu + ((u >> 16) & 1u)) >> 16;   // RNE, inputs finite
}

__device__ __forceinline__ void async_load16(const void* g, void* l) {
  __builtin_amdgcn_global_load_lds(
      (__attribute__((address_space(1))) void*)g,
      (__attribute__((address_space(3))) void*)l, 16, 0, 0);
}

// ---- prep (single dispatch): xd rows + halo + weight frag-relayout ---------
// Blocks 0..511   : one (n,y) row. Coalesced float2 reads of x, scale by
//                   depth, c-major LDS transpose, coalesced NHWC writes.
// Blocks 512..515 : zero halo rows 0 and 129 of image n.
// Blocks 516..579 : wt2 in MFMA-A-fragment order, contiguous per (s,T):
//   gid = o0*147456 + s*4096 + T*512 + lane*8 + j   (shorts)
//   o = o0*128 + T*16 + (lane&15)
//   cc = s/9; tap = s%9; c = cc*32 + (lane>>4)*8 + j
__global__ __launch_bounds__(256) void prep_all(const float* __restrict__ x,
                                                const float* __restrict__ depth,
                                                const float* __restrict__ w,
                                                short* __restrict__ xd,
                                                short* __restrict__ wt2) {
  const int R = blockIdx.x;
  const int tid = threadIdx.x;

  if (R >= NB * HW + NB) {                  // ---- weight blocks
    int gid = (R - (NB * HW + NB)) * 4608 + tid;   // 64 * 4608 = 294912
#pragma unroll
    for (int i = 0; i < 18; ++i, gid += 256) {
      const int j = gid & 7;
      const int lane = (gid >> 3) & 63;
      const int T = (gid >> 9) & 7;        // frag row-block 0..7 (o = T*16+ln)
      const int g2 = gid >> 12;
      const int s = g2 % 36;               // K-slot in conv order: cc*9 + tap
      const int o0 = g2 / 36;
      const int ln = lane & 15, q = lane >> 4;
      const int o = (o0 << 7) + (T << 4) + ln;
      const int cc = s / 9;
      const int tap = s % 9;
      const int c = (cc << 5) + (q << 3) + j;
      wt2[gid] = (short)f2bf_bits(w[((size_t)o * C_IN + c) * 9 + tap]);
    }
    return;
  }

  if (R >= NB * HW) {                       // ---- halo-row zero blocks
    const int n = R - NB * HW;
    uint4v* base0 = (uint4v*)(xd + (size_t)n * PADW * PADW * C_IN);
    uint4v* base1 = (uint4v*)(xd + ((size_t)n * PADW + (PADW - 1)) * PADW * C_IN);
    const uint4v z = {0u, 0u, 0u, 0u};
    const int per_row = PADW * C_IN * 2 / 16;   // 2080 uint4 per padded row
    for (int i = tid; i < per_row; i += 256) {
      base0[i] = z;
      base1[i] = z;
    }
    return;
  }

  // ---- row-transform blocks (R6 version)
  __shared__ short s[C_IN * PADW];   // c-major: s[c*130 + px]

  const int n = R >> 7, y = R & 127;
  const int lane = tid & 63;
  const int wave = tid >> 6;

  // zero the two edge pixels of this padded row (x=0 and x=129)
  {
    unsigned* row = (unsigned*)(xd + ((size_t)(n * PADW + y + 1) * PADW) * C_IN);
    if (tid < 64) row[tid] = 0u;                              // pixel 0
    else if (tid < 128) row[(size_t)(PADW - 1) * 64 + (tid - 64)] = 0u;  // pixel 129
  }

  // phase 1: read x (float2, coalesced), scale, dword-write to LDS (c-major)
  const f32x2 d2 = *(const f32x2*)(depth + ((size_t)n * HW + y) * HW + 2 * lane);
  const float* xrow = x + (((size_t)n * C_IN) * HW + y) * HW + 2 * lane;
  unsigned* s32 = (unsigned*)s;
#pragma unroll 8
  for (int ci = 0; ci < 32; ++ci) {
    const int c = ci * 4 + wave;
    const f32x2 v = *(const f32x2*)(xrow + (size_t)c * HW * HW);
    s32[c * 65 + lane] = f2bf_bits(v.x * d2.x) | (f2bf_bits(v.y * d2.y) << 16);
  }
  __syncthreads();

  // phase 2: coalesced NHWC write (pixels 1..128 of the padded row)
  const unsigned short* s16 = (const unsigned short*)s;
  unsigned* orow = (unsigned*)(xd + ((size_t)(n * PADW + y + 1) * PADW + 1) * C_IN);
#pragma unroll 8
  for (int i = 0; i < 32; ++i) {
    const int flat = tid + i * 256;      // 0..8191 dwords
    const int px = flat >> 6, cp = flat & 63;
    const unsigned lo = s16[(2 * cp) * PADW + px];
    const unsigned hi = s16[(2 * cp + 1) * PADW + px];
    orow[flat] = lo | (hi << 16);
  }
}

// ---- main MFMA implicit-GEMM conv ------------------------------------------
// Block: 256 threads (4 waves, 2x2), tile 128(o) x 256(px = 2 output rows).
// Wave tile 64(o) x 128(px): acc 4x8. K = 1152 as (cc 0..3) x (tap 0..8).
// Double-buffered strips; next-phase global_load_lds chunks spread across
// taps AFTER each tap's a-prefetch. One barrier per phase boundary.
// Flat 512-block grid with XCD swizzle: swz = (bid&7)*64 + (bid>>3); each
// XCD owns 32 consecutive bx (xd slice ~2.1MB -> L2-resident) and the two
// o0b tiles of each bx are time-adjacent (second strip read is an L2 hit).
__global__ __launch_bounds__(256, 2) void conv_mfma(
    const short* __restrict__ xd, const short* __restrict__ wt2,
    const float* __restrict__ bias, float* __restrict__ out) {
  __shared__ __align__(16) short xbuf[2][16640];   // 2 x [px_strip 520][32 ch]

  const int tid = threadIdx.x;
  const int swz = ((blockIdx.x & 7) << 6) + (blockIdx.x >> 3);  // 0..511, XCD-contig
  const int o0b = swz & 1;              // o tile (x128)
  const int bx = swz >> 1;              // n*64 + ypair, 0..255
  const int n = bx >> 6;
  const int y = (bx & 63) << 1;         // first of two output rows
  const int lane = tid & 63;
  const int wave = tid >> 6;
  const int wm = wave & 1, wn = wave >> 1;
  const int ln = lane & 15, q = lane >> 4;

  // W fragment stream base (shorts): frag (s,T) contiguous 1KB, T = wm*4+t
  const short* wbase = wt2 + (size_t)o0b * 147456 + (wm << 11) + (lane << 3);

  // X strip staging: LDS chunk c = tid + j*256 (linear), global source chunk
  // pre-swizzled: q_src = (tid&3) ^ ((tid>>3)&3)  (== (c&3)^((c>>3)&3) for
  // all j since j*256 keeps both fields). px term unchanged.
  const short* xsrc0 = xd + (size_t)(n * PADW + y) * PADW * C_IN +
                       (tid >> 2) * C_IN + ((tid & 3) ^ ((tid >> 3) & 3)) * 8;

  f32x4 acc[4][8] = {};
  short8 areg[2][4];

  auto loadA = [&](int s, int p) {
#pragma unroll
    for (int t = 0; t < 4; ++t)
      areg[p][t] = *(const short8*)(wbase + (size_t)s * 4096 + t * 512);
  };

  {  // prologue: stage strip cc=0 into buf0
    short* xdst = &xbuf[0][0] + tid * 8;
#pragma unroll
    for (int j = 0; j < 8; ++j)
      async_load16(xsrc0 + j * 8192, xdst + j * 2048);
    if (tid < 32) async_load16(xsrc0 + 8 * 8192, xdst + 8 * 2048);
  }
  loadA(0, 0);
  __syncthreads();   // buf0 ready

#pragma unroll
  for (int cc = 0; cc < 4; ++cc) {
#pragma unroll
    for (int tap = 0; tap < 9; ++tap) {
      const int s = cc * 9 + tap;
      if (s + 1 < 36) loadA(s + 1, (s + 1) & 1);   // prefetch next a-frags

      if (cc + 1 < 4) {   // spread next-strip staging across taps (after loadA!)
        const short* sp = xsrc0 + ((cc + 1) << 5);
        short* xdst = &xbuf[(cc + 1) & 1][0] + tid * 8;
        if (tap < 8) async_load16(sp + tap * 8192, xdst + tap * 2048);
        if (tap == 0 && tid < 32)
          async_load16(sp + 8 * 8192, xdst + 8 * 2048);  // tail 32 chunks
      }

      const int ti = tap / 3, tj = tap % 3;        // static under unroll
      const int rbase = (wn + ti) * 130 + tj;      // strip row + col shift

      short8 b[8];
#pragma unroll
      for (int u = 0; u < 8; ++u) {
        const int px = rbase + (u << 4) + ln;
        const int qx = (q ^ ((px >> 1) & 3)) << 3; // bank swizzle (q-field)
        b[u] = *(const short8*)(&xbuf[cc & 1][0] + px * 32 + qx);
      }
      __builtin_amdgcn_s_setprio(1);
#pragma unroll
      for (int t = 0; t < 4; ++t)
#pragma unroll
        for (int u = 0; u < 8; ++u)
          acc[t][u] = __builtin_amdgcn_mfma_f32_16x16x32_bf16(
              areg[s & 1][t], b[u], acc[t][u], 0, 0, 0);
      __builtin_amdgcn_s_setprio(0);
    }
    if (cc + 1 < 4) __syncthreads();   // buf(cc+1) staged+drained; buf(cc) free
  }

  // epilogue: D layout col=lane&15 (pixel), row=q*4+r (o)
  const int yrow = y + wn;
#pragma unroll
  for (int t = 0; t < 4; ++t) {
    const int ob = (o0b << 7) + (wm << 6) + (t << 4) + (q << 2);
#pragma unroll
    for (int u = 0; u < 8; ++u) {
      const int xcol = (u << 4) + ln;           // 0..127
#pragma unroll
      for (int r = 0; r < 4; ++r) {
        const int o = ob + r;
        out[(((size_t)n * O_OUT + o) * HW + yrow) * HW + xcol] =
            acc[t][u][r] + bias[o];
      }
    }
  }
}

// ---- fallback (only if ws_size is too small): naive direct conv ------------
__global__ void conv_naive(const float* __restrict__ x,
                           const float* __restrict__ depth,
                           const float* __restrict__ w,
                           const float* __restrict__ bias,
                           float* __restrict__ out) {
  const int gid = blockIdx.x * 256 + threadIdx.x;
  if (gid >= NB * O_OUT * HW * HW) return;
  const int xc = gid & 127;
  const int y = (gid >> 7) & 127;
  const int o = (gid >> 14) & 255;
  const int n = gid >> 22;
  float s = bias[o];
  for (int c = 0; c < C_IN; ++c)
    for (int i = 0; i < 3; ++i) {
      const int yy = y + i - 1;
      if (yy < 0 || yy >= HW) continue;
      for (int j = 0; j < 3; ++j) {
        const int xx = xc + j - 1;
        if (xx < 0 || xx >= HW) continue;
        s += w[((o * C_IN + c) * 3 + i) * 3 + j] *
             x[(((size_t)n * C_IN + c) * HW + yy) * HW + xx] *
             depth[((size_t)n * HW + yy) * HW + xx];
      }
    }
  out[gid] = s;
}

extern "C" void kernel_launch(void* const* d_in, const int* in_sizes, int n_in,
                              void* d_out, int out_size, void* d_ws, size_t ws_size,
                              hipStream_t stream) {
  const float* x = (const float*)d_in[0];
  const float* depth = (const float*)d_in[1];
  // d_in[2] = camera_params (unused by reference)
  const float* weight = (const float*)d_in[3];
  const float* bias = (const float*)d_in[4];
  float* out = (float*)d_out;

  const size_t need = XD_BYTES + WT_BYTES;
  if (ws_size < need) {
    conv_naive<<<(NB * O_OUT * HW * HW + 255) / 256, 256, 0, stream>>>(
        x, depth, weight, bias, out);
    return;
  }

  short* xd = (short*)d_ws;
  short* wt2 = (short*)((char*)d_ws + XD_BYTES);

  prep_all<<<NB * HW + NB + 64, 256, 0, stream>>>(x, depth, weight, xd, wt2);
  conv_mfma<<<dim3(NB * HW), 256, 0, stream>>>(xd, wt2, bias, out);
}